// Round 12
// baseline (72.088 us; speedup 1.0000x reference)
//
#include <hip/hip_runtime.h>
#include <float.h>

// Chamfer distance, B=16, N=2048, D=3, fp32 — INSTRUMENTATION ROUND.
// Byte-identical to round 7 (23.9 us anchor), except cd_min_kernel is
// dispatched 5x (idempotent: plain stores of identical values). Then
// total = 23.9 + 4*T_min, isolating the min kernel's true duration,
// which rocprof top-5 cannot show (harness poison fills fill the table).

constexpr int B_ = 16;
constexpr int N_ = 2048;
constexpr int THREADS = 256;
constexpr int QPT = 8;                  // queries per thread; THREADS*QPT == N_
constexpr int NJC = 32;                 // ref chunks
constexpr int CHUNK = N_ / NJC;         // 64 refs per chunk
constexpr int SLICES = N_ / THREADS;    // 8 combine slices per (dir,b)

typedef float v4f __attribute__((ext_vector_type(4)));

// ws layout: float partial[2][B_][NJC][N_], then float sums[2][B_][SLICES]

__global__ __launch_bounds__(THREADS)
void cd_min_kernel(const float* __restrict__ x,
                   const float* __restrict__ y,
                   float* __restrict__ partial) {
    const int jc  = blockIdx.x;
    const int b   = blockIdx.y;
    const int dir = blockIdx.z;

    const float* __restrict__ q = dir ? y : x;
    const float* __restrict__ r = dir ? x : y;

    __shared__ float lref[4][CHUNK];    // [x|y|z|0.5*|r|^2][point]
    {
        const float* __restrict__ rp =
            r + ((size_t)b * N_ + (size_t)jc * CHUNK) * 3;
        for (int p = (int)threadIdx.x; p < CHUNK; p += THREADS) {
            const float rx = rp[3 * p + 0];
            const float ry = rp[3 * p + 1];
            const float rz = rp[3 * p + 2];
            lref[0][p] = rx;
            lref[1][p] = ry;
            lref[2][p] = rz;
            lref[3][p] = 0.5f * (rx * rx + ry * ry + rz * rz);
        }
    }

    const int i0 = (int)threadIdx.x * QPT;
    const float* qp = q + ((size_t)b * N_ + i0) * 3;

    float qf[24];
    {
        const float4* qv = (const float4*)qp;
        #pragma unroll
        for (int v = 0; v < 6; ++v) {
            const float4 t = qv[v];
            qf[4 * v + 0] = t.x; qf[4 * v + 1] = t.y;
            qf[4 * v + 2] = t.z; qf[4 * v + 3] = t.w;
        }
    }
    float qnx[QPT], qny[QPT], qnz[QPT], q2[QPT], best[QPT];
    #pragma unroll
    for (int k = 0; k < QPT; ++k) {
        const float a0 = qf[3 * k + 0];
        const float a1 = qf[3 * k + 1];
        const float a2 = qf[3 * k + 2];
        qnx[k] = -a0; qny[k] = -a1; qnz[k] = -a2;
        q2[k]  = a0 * a0 + a1 * a1 + a2 * a2;
        best[k] = FLT_MAX;
    }
    __syncthreads();

    const v4f* __restrict__ lx = (const v4f*)lref[0];
    const v4f* __restrict__ ly = (const v4f*)lref[1];
    const v4f* __restrict__ lz = (const v4f*)lref[2];
    const v4f* __restrict__ lh = (const v4f*)lref[3];

    #pragma unroll 2
    for (int g = 0; g < CHUNK / 4; ++g) {
        const v4f X = lx[g], Y = ly[g], Z = lz[g], H = lh[g];
        #pragma unroll
        for (int k = 0; k < QPT; ++k) {
            float a0 = fmaf(qnx[k], X.x, H.x);
            a0 = fmaf(qny[k], Y.x, a0);
            a0 = fmaf(qnz[k], Z.x, a0);
            float a1 = fmaf(qnx[k], X.y, H.y);
            a1 = fmaf(qny[k], Y.y, a1);
            a1 = fmaf(qnz[k], Z.y, a1);
            float a2 = fmaf(qnx[k], X.z, H.z);
            a2 = fmaf(qny[k], Y.z, a2);
            a2 = fmaf(qnz[k], Z.z, a2);
            float a3 = fmaf(qnx[k], X.w, H.w);
            a3 = fmaf(qny[k], Y.w, a3);
            a3 = fmaf(qnz[k], Z.w, a3);
            best[k] = fminf(fminf(best[k], a0), a1);
            best[k] = fminf(fminf(best[k], a2), a3);
        }
    }

    float res[QPT];
    #pragma unroll
    for (int k = 0; k < QPT; ++k)
        res[k] = 2.0f * best[k] + q2[k];

    float4* op = (float4*)(partial
        + (((size_t)dir * B_ + b) * NJC + jc) * N_ + i0);
    op[0] = *(float4*)&res[0];
    op[1] = *(float4*)&res[4];
}

__global__ __launch_bounds__(THREADS)
void cd_combine_kernel(const float* __restrict__ partial,
                       float* __restrict__ sums) {
    const int b     = blockIdx.x;
    const int dir   = blockIdx.y;
    const int slice = blockIdx.z;
    const int t     = (int)threadIdx.x;
    const int i     = slice * THREADS + t;

    const float* __restrict__ p =
        partial + ((size_t)dir * B_ + b) * (size_t)NJC * N_ + i;

    float m = FLT_MAX;
    #pragma unroll
    for (int c = 0; c < NJC; ++c)
        m = fminf(m, p[(size_t)c * N_]);

    float s = m;
    #pragma unroll
    for (int o = 32; o > 0; o >>= 1)
        s += __shfl_down(s, o, 64);

    __shared__ float red[THREADS / 64];
    if ((t & 63) == 0) red[t >> 6] = s;
    __syncthreads();
    if (t == 0) {
        float tot = 0.0f;
        #pragma unroll
        for (int w = 0; w < THREADS / 64; ++w) tot += red[w];
        sums[((size_t)dir * B_ + b) * SLICES + slice] = tot;
    }
}

__global__ __launch_bounds__(THREADS)
void cd_final_kernel(const float* __restrict__ sums,
                     float* __restrict__ out) {
    const int t   = (int)threadIdx.x;
    const int b   = t >> 4;
    const int k   = t & 15;
    const int dir = k >> 3;
    const int sl  = k & 7;

    float v = sums[((size_t)dir * B_ + b) * SLICES + sl];
    v += __shfl_down(v, 8, 16);
    v += __shfl_down(v, 4, 16);
    v += __shfl_down(v, 2, 16);
    v += __shfl_down(v, 1, 16);
    if (k == 0) out[b] = v * (1.0f / (float)N_);
}

extern "C" void kernel_launch(void* const* d_in, const int* in_sizes, int n_in,
                              void* d_out, int out_size, void* d_ws, size_t ws_size,
                              hipStream_t stream) {
    const float* x = (const float*)d_in[0];
    const float* y = (const float*)d_in[1];
    float* out     = (float*)d_out;
    float* partial = (float*)d_ws;   // 8 MiB + sums

    float* sums = partial + 2ull * B_ * NJC * N_;

    // 5x min dispatch: idempotent (same inputs -> same stores). The extra
    // 4 dispatches exist purely to measure T_min via total-time delta.
    for (int rep = 0; rep < 5; ++rep)
        cd_min_kernel<<<dim3(NJC, B_, 2), dim3(THREADS), 0, stream>>>(x, y, partial);
    cd_combine_kernel<<<dim3(B_, 2, SLICES), dim3(THREADS), 0, stream>>>(partial, sums);
    cd_final_kernel<<<dim3(1), dim3(THREADS), 0, stream>>>(sums, out);
}

// Round 13
// 40.631 us; speedup vs baseline: 1.7742x; 1.7742x over previous
//
#include <hip/hip_runtime.h>
#include <float.h>

// Chamfer distance, B=16, N=2048, D=3, fp32 — MFMA path.
// P_ij/2 = h_i + h_j - x_i.y_j, h = 0.5|.|^2.
// bf16 hi/lo split packed into K of ONE v_mfma_f32_32x32x16_bf16:
//   A k-slots [-xh0..2, -xl0..2, -xh0..2], B k-slots [yh0..2, yh0..2, yl0..2]
//   => A.B = -(xh.yh + xl.yh + xh.yl) = -x.y (+/- ~2e-4, drops xl.yl)
// C operand preloaded with hh = h_i + h_j  =>  D = P/2 directly.
// Row-mins (dr) and col-mins (dl) both harvested from the SAME tile:
// each (i,j) evaluated ONCE (vs twice in all scalar rounds).
// Reduction: global atomicMin on sign-flip-encoded fp32 keys (exact min,
// deterministic) into 0xFF-initialized ws; small decode+sum kernel.
// C/D layout (HW-verified m74/m101): col=lane&31, row=(reg&3)+8(reg>>2)+4(lane>>5).
// A/B assumed standard CDNA: row/col = lane&31, k = 8*(lane>>5)+elem.

constexpr int B_ = 16;
constexpr int N_ = 2048;
constexpr int THREADS = 256;
constexpr int NJH = 1024;                 // j-points staged per block
constexpr int JT_PER_WAVE = 8;            // (NJH/32) / 4 waves

typedef float f32x16 __attribute__((ext_vector_type(16)));
typedef short s16x8  __attribute__((ext_vector_type(8)));

__device__ __forceinline__ unsigned short to_bf16(float f) {
    unsigned u = __float_as_uint(f);
    u += 0x7FFFu + ((u >> 16) & 1u);      // RNE
    return (unsigned short)(u >> 16);
}
__device__ __forceinline__ float from_bf16(unsigned short h) {
    return __uint_as_float(((unsigned)h) << 16);
}
// Monotonic float->uint key: fkey(a) < fkey(b) <=> a < b. Max key 0xFF800000.
__device__ __forceinline__ unsigned fkey(float f) {
    int b = __float_as_int(f);
    unsigned m = (b < 0) ? 0xFFFFFFFFu : 0x80000000u;
    return ((unsigned)b) ^ m;
}
__device__ __forceinline__ float fdec(unsigned k) {
    int b = (k & 0x80000000u) ? (int)(k ^ 0x80000000u) : (int)(~k);
    return __int_as_float(b);
}

// grid (64 itiles, 16 b, 2 jh). Block: i-tile (32 x-pts) vs 1024 y-pts.
// ws: unsigned dmin[2][B_][N_]: [0]=row mins (dr, per i), [1]=col mins (dl, per j).
__global__ __launch_bounds__(THREADS)
void cd_mfma_kernel(const float* __restrict__ x,
                    const float* __restrict__ y,
                    unsigned* __restrict__ drow,
                    unsigned* __restrict__ dcol) {
    const int itile = blockIdx.x;
    const int b     = blockIdx.y;
    const int jh    = blockIdx.z;
    const int t     = (int)threadIdx.x;
    const int lane  = t & 63;
    const int wv    = t >> 6;
    const int lc    = lane & 31;          // row (A) / col (B) within tile
    const int hf    = lane >> 5;          // k-half

    __shared__ __align__(16) unsigned short ldsB[2][NJH][8];  // 32 KB packed B-frags
    __shared__ float lds_hy[NJH];                             // 4 KB
    __shared__ float lds_hx[32];

    // ---- stage 4 y-points per thread: split, pack both k-half frags ----
    {
        const int p0 = t * 4;
        const float* yp = y + ((size_t)b * N_ + (size_t)jh * NJH + p0) * 3;
        const float4 v0 = ((const float4*)yp)[0];
        const float4 v1 = ((const float4*)yp)[1];
        const float4 v2 = ((const float4*)yp)[2];
        const float c[12] = {v0.x, v0.y, v0.z, v0.w,
                             v1.x, v1.y, v1.z, v1.w,
                             v2.x, v2.y, v2.z, v2.w};
        #pragma unroll
        for (int p = 0; p < 4; ++p) {
            const float fx = c[3 * p + 0], fy = c[3 * p + 1], fz = c[3 * p + 2];
            const unsigned short h0 = to_bf16(fx), h1 = to_bf16(fy), h2 = to_bf16(fz);
            const unsigned short l0 = to_bf16(fx - from_bf16(h0));
            const unsigned short l1 = to_bf16(fy - from_bf16(h1));
            const unsigned short l2 = to_bf16(fz - from_bf16(h2));
            uint4 w0, w1;
            w0.x = (unsigned)h0 | ((unsigned)h1 << 16);   // [yh0 yh1]
            w0.y = (unsigned)h2 | ((unsigned)h0 << 16);   // [yh2 yh0]
            w0.z = (unsigned)h1 | ((unsigned)h2 << 16);   // [yh1 yh2]
            w0.w = (unsigned)l0 | ((unsigned)l1 << 16);   // [yl0 yl1]
            w1.x = (unsigned)l2; w1.y = 0; w1.z = 0; w1.w = 0;
            *(uint4*)&ldsB[0][p0 + p][0] = w0;
            *(uint4*)&ldsB[1][p0 + p][0] = w1;
            lds_hy[p0 + p] = 0.5f * (fx * fx + fy * fy + fz * fz);
        }
    }
    if (t < 32) {
        const float* xp = x + ((size_t)b * N_ + (size_t)itile * 32 + t) * 3;
        const float a = xp[0], bb = xp[1], cc = xp[2];
        lds_hx[t] = 0.5f * (a * a + bb * bb + cc * cc);
    }

    // ---- per-lane A fragment: negated x splits, k-half by hf ----
    s16x8 af;
    {
        const float* xp = x + ((size_t)b * N_ + (size_t)itile * 32 + lc) * 3;
        const float ax = -xp[0], ay = -xp[1], az = -xp[2];
        const unsigned short xh0 = to_bf16(ax), xh1 = to_bf16(ay), xh2 = to_bf16(az);
        const unsigned short xl0 = to_bf16(ax - from_bf16(xh0));
        const unsigned short xl1 = to_bf16(ay - from_bf16(xh1));
        const unsigned short xl2 = to_bf16(az - from_bf16(xh2));
        if (hf == 0) {
            af[0] = (short)xh0; af[1] = (short)xh1; af[2] = (short)xh2;
            af[3] = (short)xl0; af[4] = (short)xl1; af[5] = (short)xl2;
            af[6] = (short)xh0; af[7] = (short)xh1;
        } else {
            af[0] = (short)xh2; af[1] = 0; af[2] = 0; af[3] = 0;
            af[4] = 0; af[5] = 0; af[6] = 0; af[7] = 0;
        }
    }
    __syncthreads();

    float hxr[16];
    #pragma unroll
    for (int r = 0; r < 16; ++r)
        hxr[r] = lds_hx[(r & 3) + 8 * (r >> 2) + 4 * hf];

    float runmin[16];
    #pragma unroll
    for (int r = 0; r < 16; ++r) runmin[r] = FLT_MAX;

    // ---- main loop: 8 tiles per wave, 1 MFMA each ----
    const int jt0 = wv * JT_PER_WAVE;
    for (int n = 0; n < JT_PER_WAVE; ++n) {
        const int jl = (jt0 + n) * 32 + lc;
        const float hy = lds_hy[jl];
        const s16x8 bf = *(const s16x8*)&ldsB[hf][jl][0];
        f32x16 hh;
        #pragma unroll
        for (int r = 0; r < 16; ++r) hh[r] = hxr[r] + hy;
        const f32x16 acc =
            __builtin_amdgcn_mfma_f32_32x32x16_bf16(af, bf, hh, 0, 0, 0);
        // rows (dr): running min per reg
        #pragma unroll
        for (int r = 0; r < 16; ++r) runmin[r] = fminf(runmin[r], acc[r]);
        // cols (dl): min over the 16 rows this lane holds, then lane^32
        const float c0 = fminf(fminf(acc[0], acc[1]),  fminf(acc[2], acc[3]));
        const float c1 = fminf(fminf(acc[4], acc[5]),  fminf(acc[6], acc[7]));
        const float c2 = fminf(fminf(acc[8], acc[9]),  fminf(acc[10], acc[11]));
        const float c3 = fminf(fminf(acc[12], acc[13]), fminf(acc[14], acc[15]));
        float cw = fminf(fminf(c0, c1), fminf(c2, c3));
        cw = fminf(cw, __shfl_xor(cw, 32, 64));
        if (hf == 0)
            atomicMin(&dcol[(size_t)b * N_ + (size_t)jh * NJH + jl], fkey(cw));
    }

    // ---- row finale: reduce across the 32 lanes of each half ----
    #pragma unroll
    for (int r = 0; r < 16; ++r) {
        float v = runmin[r];
        v = fminf(v, __shfl_xor(v, 1, 64));
        v = fminf(v, __shfl_xor(v, 2, 64));
        v = fminf(v, __shfl_xor(v, 4, 64));
        v = fminf(v, __shfl_xor(v, 8, 64));
        v = fminf(v, __shfl_xor(v, 16, 64));
        runmin[r] = v;
    }
    if (lc == 0) {
        #pragma unroll
        for (int r = 0; r < 16; ++r)
            atomicMin(&drow[(size_t)b * N_ + (size_t)itile * 32
                            + (r & 3) + 8 * (r >> 2) + 4 * hf],
                      fkey(runmin[r]));
    }
}

// Decode + sum: out[b] = (2/N) * (sum_i wr[i] + sum_j wc[j]).
__global__ __launch_bounds__(THREADS)
void cd_sum_kernel(const unsigned* __restrict__ dmin,
                   float* __restrict__ out) {
    const int b = blockIdx.x;
    const int t = (int)threadIdx.x;

    float s = 0.0f;
    #pragma unroll
    for (int part = 0; part < 2; ++part) {
        const unsigned* p = dmin + (size_t)part * B_ * N_ + (size_t)b * N_ + t * 8;
        const uint4 u0 = ((const uint4*)p)[0];
        const uint4 u1 = ((const uint4*)p)[1];
        s += fdec(u0.x) + fdec(u0.y) + fdec(u0.z) + fdec(u0.w)
           + fdec(u1.x) + fdec(u1.y) + fdec(u1.z) + fdec(u1.w);
    }
    #pragma unroll
    for (int o = 32; o > 0; o >>= 1)
        s += __shfl_down(s, o, 64);

    __shared__ float red[THREADS / 64];
    if ((t & 63) == 0) red[t >> 6] = s;
    __syncthreads();
    if (t == 0) {
        float tot = 0.0f;
        #pragma unroll
        for (int w = 0; w < THREADS / 64; ++w) tot += red[w];
        out[b] = tot * (2.0f / (float)N_);
    }
}

extern "C" void kernel_launch(void* const* d_in, const int* in_sizes, int n_in,
                              void* d_out, int out_size, void* d_ws, size_t ws_size,
                              hipStream_t stream) {
    const float* x = (const float*)d_in[0];
    const float* y = (const float*)d_in[1];
    float* out     = (float*)d_out;
    unsigned* dmin = (unsigned*)d_ws;     // 2*16*2048 uints = 256 KiB

    hipMemsetAsync(d_ws, 0xFF, 2ull * B_ * N_ * sizeof(unsigned), stream);
    cd_mfma_kernel<<<dim3(64, B_, 2), dim3(THREADS), 0, stream>>>(
        x, y, dmin, dmin + (size_t)B_ * N_);
    cd_sum_kernel<<<dim3(B_), dim3(THREADS), 0, stream>>>(dmin, out);
}